// Round 1
// baseline (556.806 us; speedup 1.0000x reference)
//
#include <hip/hip_runtime.h>
#include <stdint.h>
#include <stddef.h>

// BinaryLinearLayer: out[8192,4096] = x[8192,4096] @ sign(W[4096,4096])^T + sign(bias)[4096]
// Strategy: cast x -> bf16, sign(W) -> bf16 (+-1 exact in bf16), then m97-style
// MFMA bf16 GEMM (128x128 tile, BK=32, 16x16x32 mfma, global_load_lds width 16).
// Fallback (ws too small): fused kernel converting during LDS staging.

#define MDIM 8192
#define NDIM 4096
#define KDIM 4096

typedef __attribute__((ext_vector_type(8))) short bf16x8;
typedef __attribute__((ext_vector_type(4))) float f32x4;

__device__ __forceinline__ short f2bf(float f) {
  union { float f; unsigned u; } a; a.f = f;
  unsigned r = a.u + 0x7FFFu + ((a.u >> 16) & 1u);
  return (short)(r >> 16);
}

__device__ __forceinline__ float fsign(float x) {
  return (x > 0.f) ? 1.f : ((x < 0.f) ? -1.f : 0.f);
}

// sign(x) directly as bf16 bits: +1 -> 0x3F80, -1 -> 0xBF80, 0 -> 0
__device__ __forceinline__ short signbf(float x) {
  return (x > 0.f) ? (short)0x3F80 : ((x < 0.f) ? (short)0xBF80 : (short)0);
}

__device__ __forceinline__ void gl_lds16(const void* g, void* l) {
  __builtin_amdgcn_global_load_lds(
      (const __attribute__((address_space(1))) unsigned*)g,
      (__attribute__((address_space(3))) unsigned*)l,
      16, 0, 0);
}

// ---------------- conversion kernels (path A) ----------------

__global__ void cvt_x_kernel(const float* __restrict__ x, short* __restrict__ o) {
  int i = blockIdx.x * blockDim.x + threadIdx.x;          // one float4 per thread
  float4 v = ((const float4*)x)[i];
  short4 s;
  s.x = f2bf(v.x); s.y = f2bf(v.y); s.z = f2bf(v.z); s.w = f2bf(v.w);
  ((short4*)o)[i] = s;
}

__global__ void cvt_w_kernel(const float* __restrict__ w, short* __restrict__ o) {
  int i = blockIdx.x * blockDim.x + threadIdx.x;
  float4 v = ((const float4*)w)[i];
  short4 s;
  s.x = signbf(v.x); s.y = signbf(v.y); s.z = signbf(v.z); s.w = signbf(v.w);
  ((short4*)o)[i] = s;
}

// ---------------- main GEMM, bf16 operands from ws (path A) ----------------
// C[m,n] = sum_k A[m,k]*B[n,k] + sign(bias[n]);  A,B row-major K-contiguous.

__global__ __launch_bounds__(256) void gemm_ws(
    const short* __restrict__ A,   // [MDIM, KDIM] bf16
    const short* __restrict__ B,   // [NDIM, KDIM] bf16 (signs)
    const float* __restrict__ bias,
    float* __restrict__ C) {
  __shared__ short As[128 * 32];   // 8 KB, row-major rows of 32 bf16 (64 B)
  __shared__ short Bs[128 * 32];

  const int t    = threadIdx.x;
  const int lane = t & 63;
  const int wm   = (t >> 6) >> 1;   // wave row 0..1
  const int wn   = (t >> 6) & 1;    // wave col 0..1

  const int bm = blockIdx.y * 128;
  const int bn = blockIdx.x * 128;

  f32x4 acc[4][4] = {};

  // staging: thread t covers LDS bytes [t*16, t*16+16) => row t/4, k-offset (t%4)*8
  const int srow = t >> 2;
  const int scol = (t & 3) << 3;

  const short* aA0 = A + (size_t)(bm + srow) * KDIM + scol;
  const short* aA1 = A + (size_t)(bm + 64 + srow) * KDIM + scol;
  const short* aB0 = B + (size_t)(bn + srow) * KDIM + scol;
  const short* aB1 = B + (size_t)(bn + 64 + srow) * KDIM + scol;

  char* ldsA0 = (char*)As + t * 16;
  char* ldsA1 = (char*)As + 4096 + t * 16;
  char* ldsB0 = (char*)Bs + t * 16;
  char* ldsB1 = (char*)Bs + 4096 + t * 16;

  const int fr  = lane & 15;             // fragment row within 16
  const int fkB = (lane >> 4) << 4;      // k-group byte offset: (lane>>4)*8 elems * 2B

  for (int k0 = 0; k0 < KDIM; k0 += 32) {
    gl_lds16(aA0 + k0, ldsA0);
    gl_lds16(aA1 + k0, ldsA1);
    gl_lds16(aB0 + k0, ldsB0);
    gl_lds16(aB1 + k0, ldsB1);
    __syncthreads();   // compiler emits vmcnt(0) drain before barrier -> LDS ready

    bf16x8 af[4], bfr[4];
#pragma unroll
    for (int i = 0; i < 4; ++i) {
      af[i]  = *(const bf16x8*)((const char*)As + (wm * 64 + i * 16 + fr) * 64 + fkB);
      bfr[i] = *(const bf16x8*)((const char*)Bs + (wn * 64 + i * 16 + fr) * 64 + fkB);
    }
#pragma unroll
    for (int i = 0; i < 4; ++i)
#pragma unroll
      for (int j = 0; j < 4; ++j)
        acc[i][j] = __builtin_amdgcn_mfma_f32_16x16x32_bf16(af[i], bfr[j], acc[i][j], 0, 0, 0);
    __syncthreads();   // all LDS reads done before next iteration's loads overwrite
  }

  // epilogue: C/D layout col = lane&15, row = (lane>>4)*4 + r
  const int row0 = bm + wm * 64 + ((lane >> 4) << 2);
  const int col0 = bn + wn * 64 + (lane & 15);
#pragma unroll
  for (int j = 0; j < 4; ++j) {
    const int gc = col0 + j * 16;
    const float bs = fsign(bias[gc]);
#pragma unroll
    for (int i = 0; i < 4; ++i) {
      float* cp = C + (size_t)(row0 + i * 16) * NDIM + gc;
#pragma unroll
      for (int r = 0; r < 4; ++r)
        cp[(size_t)r * NDIM] = acc[i][j][r] + bs;
    }
  }
}

// ---------------- fallback: fused conversion GEMM (no workspace) ----------------

__global__ __launch_bounds__(256) void gemm_fused(
    const float* __restrict__ A,   // [MDIM, KDIM] fp32
    const float* __restrict__ W,   // [NDIM, KDIM] fp32
    const float* __restrict__ bias,
    float* __restrict__ C) {
  __shared__ short As[128 * 32];
  __shared__ short Bs[128 * 32];

  const int t    = threadIdx.x;
  const int lane = t & 63;
  const int wm   = (t >> 6) >> 1;
  const int wn   = (t >> 6) & 1;

  const int bm = blockIdx.y * 128;
  const int bn = blockIdx.x * 128;

  f32x4 acc[4][4] = {};

  // staging: thread t handles row t/2, 16 contiguous k at (t&1)*16
  const int srow = t >> 1;
  const int scol = (t & 1) << 4;

  const float* pA = A + (size_t)(bm + srow) * KDIM + scol;
  const float* pW = W + (size_t)(bn + srow) * KDIM + scol;
  short* sA = As + srow * 32 + scol;
  short* sB = Bs + srow * 32 + scol;

  const int fr  = lane & 15;
  const int fkB = (lane >> 4) << 4;

  for (int k0 = 0; k0 < KDIM; k0 += 32) {
    float4 va[4], vb[4];
#pragma unroll
    for (int q = 0; q < 4; ++q) {
      va[q] = *(const float4*)(pA + k0 + q * 4);
      vb[q] = *(const float4*)(pW + k0 + q * 4);
    }
    __syncthreads();   // previous iteration's LDS reads complete
    bf16x8 ca, cb;
#pragma unroll
    for (int q = 0; q < 4; ++q) {
      ca[q * 2 + 0] = 0; // placeholder, filled below
    }
    // convert 16 floats -> 16 bf16 each
    short va_s[16], vb_s[16];
#pragma unroll
    for (int q = 0; q < 4; ++q) {
      va_s[q * 4 + 0] = f2bf(va[q].x); va_s[q * 4 + 1] = f2bf(va[q].y);
      va_s[q * 4 + 2] = f2bf(va[q].z); va_s[q * 4 + 3] = f2bf(va[q].w);
      vb_s[q * 4 + 0] = signbf(vb[q].x); vb_s[q * 4 + 1] = signbf(vb[q].y);
      vb_s[q * 4 + 2] = signbf(vb[q].z); vb_s[q * 4 + 3] = signbf(vb[q].w);
    }
#pragma unroll
    for (int e = 0; e < 8; ++e) { ca[e] = va_s[e]; cb[e] = vb_s[e]; }
    *(bf16x8*)(sA) = ca;
    *(bf16x8*)(sB) = cb;
#pragma unroll
    for (int e = 0; e < 8; ++e) { ca[e] = va_s[8 + e]; cb[e] = vb_s[8 + e]; }
    *(bf16x8*)(sA + 8) = ca;
    *(bf16x8*)(sB + 8) = cb;
    __syncthreads();   // LDS writes visible

    bf16x8 af[4], bfr[4];
#pragma unroll
    for (int i = 0; i < 4; ++i) {
      af[i]  = *(const bf16x8*)((const char*)As + (wm * 64 + i * 16 + fr) * 64 + fkB);
      bfr[i] = *(const bf16x8*)((const char*)Bs + (wn * 64 + i * 16 + fr) * 64 + fkB);
    }
#pragma unroll
    for (int i = 0; i < 4; ++i)
#pragma unroll
      for (int j = 0; j < 4; ++j)
        acc[i][j] = __builtin_amdgcn_mfma_f32_16x16x32_bf16(af[i], bfr[j], acc[i][j], 0, 0, 0);
  }
  __syncthreads();

  const int row0 = bm + wm * 64 + ((lane >> 4) << 2);
  const int col0 = bn + wn * 64 + (lane & 15);
#pragma unroll
  for (int j = 0; j < 4; ++j) {
    const int gc = col0 + j * 16;
    const float bs = fsign(bias[gc]);
#pragma unroll
    for (int i = 0; i < 4; ++i) {
      float* cp = C + (size_t)(row0 + i * 16) * NDIM + gc;
#pragma unroll
      for (int r = 0; r < 4; ++r)
        cp[(size_t)r * NDIM] = acc[i][j][r] + bs;
    }
  }
}

extern "C" void kernel_launch(void* const* d_in, const int* in_sizes, int n_in,
                              void* d_out, int out_size, void* d_ws, size_t ws_size,
                              hipStream_t stream) {
  const float* x    = (const float*)d_in[0];
  const float* w    = (const float*)d_in[1];
  const float* bias = (const float*)d_in[2];
  float* out = (float*)d_out;

  const size_t xb_bytes = (size_t)MDIM * KDIM * 2;   // 67.1 MB
  const size_t wb_bytes = (size_t)NDIM * KDIM * 2;   // 33.6 MB

  dim3 grid(NDIM / 128, MDIM / 128);   // 32 x 64 = 2048 blocks

  if (ws_size >= xb_bytes + wb_bytes) {
    short* xb = (short*)d_ws;
    short* wb = (short*)((char*)d_ws + xb_bytes);
    cvt_x_kernel<<<(MDIM * (KDIM / 4)) / 256, 256, 0, stream>>>(x, xb);
    cvt_w_kernel<<<(NDIM * (KDIM / 4)) / 256, 256, 0, stream>>>(w, wb);
    gemm_ws<<<grid, 256, 0, stream>>>(xb, wb, bias, out);
  } else {
    gemm_fused<<<grid, 256, 0, stream>>>(x, w, bias, out);
  }
}